// Round 16
// baseline (123.015 us; speedup 1.0000x reference)
//
#include <hip/hip_runtime.h>

typedef unsigned int uint;
typedef unsigned short ushort;
typedef __attribute__((ext_vector_type(8))) short bf16x8;   // MFMA A/B frag (8 bf16)
typedef __attribute__((ext_vector_type(4))) float f32x4;    // MFMA C/D frag

// Problem constants
#define C_IN   48
#define C3     144
#define HW     56
#define SSP    3136
#define DW     49
#define DPAD   64            // padded head dim; yf cols 49..63 zero, yfT row 56 ones
#define NROWS  9216

// Attention: grid (72, 12) = 864 blocks of 4 waves (256 thr, 128 queries).
// Single K/V LDS buffer + REGISTER-staged prefetch: barriers drain lgkm only
// (the m97 vmcnt(0)-before-s_barrier stall is moved off the barrier onto the
// dependent ds_write, where it overlaps the full compute span).
// LDS 34.8 KB -> 4 blocks/CU = 16 waves/CU; 864 <= 1024 slots, all resident.
#define NSPLIT 12            // key splits
#define TPS    12            // tiles per split = 144/NSPLIT

#define CSC 0.02944245f      // 1/(49*ln2): exp2(qk*CSC)=exp(qk/49)

// ws layout (bytes):
//   yf    bf16 [9216][64]    : 0        .. 1179648
//   yfT   bf16 [64][9216]    : 1179648  .. 2359296
//   opart bf16 [12][49][9216]: 2359296  .. 13197312
//   esum  f32  [12][9216]    : 13197312 .. 13639680
#define YF_B    0
#define YFT_B   1179648
#define OPART_B 2359296
#define ESUM_B  (OPART_B + NSPLIT * DW * NROWS * 2)

__device__ __forceinline__ ushort f32_to_bf16_rne(float x) {
  uint b = __float_as_uint(x);
  b += 0x7fffu + ((b >> 16) & 1u);
  return (ushort)(b >> 16);
}
__device__ __forceinline__ float bf16_to_f32(ushort u) {
  return __uint_as_float(((uint)u) << 16);
}

// ---------------------------------------------------------------------------
// Kernel 1: depthwise convs, thread per (r,t); 2304 blocks (9 waves/SIMD).
// Writes yf[r][64] coalesced AND yfT[t][r] as a per-lane scalar scatter.
// yf cols 49..63 = 0 (K/Q pad); yfT row 56 = 1.0 (softmax denom via PV MFMA).
// yfT rows 49-55/57-63 stay garbage: each feeds only its own discarded d.
// ---------------------------------------------------------------------------
__global__ __launch_bounds__(256) void conv_kernel(
    const float* __restrict__ x, const float* __restrict__ w3,
    const float* __restrict__ w5, const float* __restrict__ w7,
    ushort* __restrict__ yf, ushort* __restrict__ yfT) {
  int idx = blockIdx.x * 256 + threadIdx.x;   // r*64 + t
  int r = idx >> 6, t = idx & 63;
  if (t >= DW) {
    yf[idx] = 0;                               // K/Q pad cols must be zero
    if (t == 56) yfT[56 * NROWS + r] = 0x3F80; // ones row -> denominator
    return;
  }
  int g = r / C3, c3 = r - g * C3;
  int flat = g * DW + t;
  int h = flat / HW, w = flat - h * HW;
  int grp = c3 / C_IN, c = c3 - grp * C_IN;
  const float* wk; int ks;
  if (grp == 0)      { wk = w3 + c * 9;  ks = 3; }
  else if (grp == 1) { wk = w5 + c * 25; ks = 5; }
  else               { wk = w7 + c * 49; ks = 7; }
  int p = ks >> 1;
  const float* xc = x + c * SSP;
  float val = 0.f;
  for (int dy = 0; dy < ks; dy++) {
    int hy = h + dy - p;
    if (hy < 0 || hy >= HW) continue;
    const float* xr = xc + hy * HW;
    const float* wr = wk + dy * ks;
    for (int dx = 0; dx < ks; dx++) {
      int wx = w + dx - p;
      if (wx < 0 || wx >= HW) continue;
      val += xr[wx] * wr[dx];
    }
  }
  ushort ov = f32_to_bf16_rne(val);
  yf[idx] = ov;
  yfT[t * NROWS + r] = ov;
}

// ---------------------------------------------------------------------------
// Kernel 2: MFMA flash attention, register-staged single-buffer pipeline.
// Grid (72, 12): blockIdx.x = 128-query block, blockIdx.y = key split (12
// tiles of 64 keys). 4 waves share ONE K/V LDS buffer; each wave owns 32
// queries end-to-end (R11-proven math).
// Pipeline per tile: loads for tile it+1 -> VGPRs (issued before compute);
// compute consumes LDS tile it; barrier A (readers done); ds_write regs->LDS
// (the vmcnt wait lands HERE, after compute overlapped the load latency);
// barrier B (lgkm-only drain); next tile.
// LDS: [K 8K][V 8K][P 4 x 32 x 72 ushort = 18432] = 34816 B.
// K slab s: d-chunk s, addr s*1024 + key*16  (s = w and w+4 per thread).
// V slab s: key-chunk s, addr s*1024 + d*16.
// yfT row 56 = ones => softmax denominator at d==56.
// ---------------------------------------------------------------------------
__global__ __launch_bounds__(256, 4) void attn_kernel(
    const ushort* __restrict__ yf, const ushort* __restrict__ yfT,
    ushort* __restrict__ opart, float* __restrict__ esum_g) {
  __shared__ __align__(16) char smem[34816];

  const int tid = threadIdx.x;
  const int w = tid >> 6, lane = tid & 63;
  const int q = lane >> 4, c = lane & 15;
  const int m0 = blockIdx.x * 128 + w * 32;   // this wave's 32 queries
  const int sp = blockIdx.y;
  char* Kb = smem;
  char* Vb = smem + 8192;
  ushort* Pm = (ushort*)(smem + 16384) + w * (32 * 72);

  const int s0 = w, s1 = w + 4;   // this thread's K/V slab pair

  // Q B-frags (pre-scaled by CSC): 16B loads straight from yf.
  bf16x8 qf[2][2];
#pragma unroll
  for (int mt = 0; mt < 2; mt++)
#pragma unroll
    for (int ds = 0; ds < 2; ds++) {
      bf16x8 raw = *(const bf16x8*)&yf[(m0 + mt * 16 + c) * 64 + ds * 32 + q * 8];
      short tmp[8];
#pragma unroll
      for (int j = 0; j < 8; j++)
        tmp[j] = (short)f32_to_bf16_rne(bf16_to_f32((ushort)raw[j]) * CSC);
      qf[mt][ds] = *(bf16x8*)tmp;
    }

  f32x4 o[4][2];
#pragma unroll
  for (int dt = 0; dt < 4; dt++)
#pragma unroll
    for (int mt = 0; mt < 2; mt++) o[dt][mt] = (f32x4)0.f;

  // ---- prologue: tile 0 -> regs -> LDS ----
  {
    const int k0 = (sp * TPS) * 64;
    uint4 kr0 = *(const uint4*)&yf[(k0 + lane) * 64 + s0 * 8];
    uint4 kr1 = *(const uint4*)&yf[(k0 + lane) * 64 + s1 * 8];
    uint4 vr0 = *(const uint4*)&yfT[lane * NROWS + k0 + s0 * 8];
    uint4 vr1 = *(const uint4*)&yfT[lane * NROWS + k0 + s1 * 8];
    *(uint4*)(Kb + s0 * 1024 + lane * 16) = kr0;
    *(uint4*)(Kb + s1 * 1024 + lane * 16) = kr1;
    *(uint4*)(Vb + s0 * 1024 + lane * 16) = vr0;
    *(uint4*)(Vb + s1 * 1024 + lane * 16) = vr1;
  }
  __syncthreads();

  for (int it = 0; it < TPS; it++) {
    // ---- issue next tile's global loads into registers ----
    uint4 kr0, kr1, vr0, vr1;
    const bool more = (it + 1 < TPS);
    if (more) {
      const int k1 = (sp * TPS + it + 1) * 64;
      kr0 = *(const uint4*)&yf[(k1 + lane) * 64 + s0 * 8];
      kr1 = *(const uint4*)&yf[(k1 + lane) * 64 + s1 * 8];
      vr0 = *(const uint4*)&yfT[lane * NROWS + k1 + s0 * 8];
      vr1 = *(const uint4*)&yfT[lane * NROWS + k1 + s1 * 8];
    }

    // ---- S^T = K . Q^T (K frags from LDS) ----
    f32x4 s[4][2];
#pragma unroll
    for (int nt = 0; nt < 4; nt++) {
      bf16x8 a0 = *(const bf16x8*)(Kb + q * 1024 + (nt * 16 + c) * 16);
      bf16x8 a1 = *(const bf16x8*)(Kb + (4 + q) * 1024 + (nt * 16 + c) * 16);
      s[nt][0] = (f32x4)0.f; s[nt][1] = (f32x4)0.f;
      s[nt][0] = __builtin_amdgcn_mfma_f32_16x16x32_bf16(a0, qf[0][0], s[nt][0], 0, 0, 0);
      s[nt][1] = __builtin_amdgcn_mfma_f32_16x16x32_bf16(a0, qf[1][0], s[nt][1], 0, 0, 0);
      s[nt][0] = __builtin_amdgcn_mfma_f32_16x16x32_bf16(a1, qf[0][1], s[nt][0], 0, 0, 0);
      s[nt][1] = __builtin_amdgcn_mfma_f32_16x16x32_bf16(a1, qf[1][1], s[nt][1], 0, 0, 0);
    }

    // ---- p = exp2(s); pack bf16 P into wave-private LDS ----
#pragma unroll
    for (int nt = 0; nt < 4; nt++)
#pragma unroll
      for (int mt = 0; mt < 2; mt++) {
        f32x4 sv = s[nt][mt];
        float p0 = __builtin_amdgcn_exp2f(sv[0]);
        float p1 = __builtin_amdgcn_exp2f(sv[1]);
        float p2 = __builtin_amdgcn_exp2f(sv[2]);
        float p3 = __builtin_amdgcn_exp2f(sv[3]);
        uint d0 = (__float_as_uint(p0) >> 16) | (__float_as_uint(p1) & 0xffff0000u);
        uint d1 = (__float_as_uint(p2) >> 16) | (__float_as_uint(p3) & 0xffff0000u);
        *(uint2*)&Pm[(mt * 16 + c) * 72 + nt * 16 + q * 4] = make_uint2(d0, d1);
      }

    // ---- O^T += V^T . P^T (V frags from LDS) ----
    bf16x8 bp[2][2];
#pragma unroll
    for (int mt = 0; mt < 2; mt++)
#pragma unroll
      for (int nc = 0; nc < 2; nc++)
        bp[mt][nc] = *(const bf16x8*)&Pm[(mt * 16 + c) * 72 + nc * 32 + q * 8];
#pragma unroll
    for (int dt = 0; dt < 4; dt++) {
      bf16x8 v0 = *(const bf16x8*)(Vb + q * 1024 + (dt * 16 + c) * 16);
      bf16x8 v1 = *(const bf16x8*)(Vb + (4 + q) * 1024 + (dt * 16 + c) * 16);
      o[dt][0] = __builtin_amdgcn_mfma_f32_16x16x32_bf16(v0, bp[0][0], o[dt][0], 0, 0, 0);
      o[dt][1] = __builtin_amdgcn_mfma_f32_16x16x32_bf16(v0, bp[1][0], o[dt][1], 0, 0, 0);
      o[dt][0] = __builtin_amdgcn_mfma_f32_16x16x32_bf16(v1, bp[0][1], o[dt][0], 0, 0, 0);
      o[dt][1] = __builtin_amdgcn_mfma_f32_16x16x32_bf16(v1, bp[1][1], o[dt][1], 0, 0, 0);
    }

    if (more) {
      __syncthreads();   // A: all waves done READING Kb/Vb (no vmem pending
                         // besides our reg loads, whose wait lands below)
      *(uint4*)(Kb + s0 * 1024 + lane * 16) = kr0;   // vmcnt wait here,
      *(uint4*)(Kb + s1 * 1024 + lane * 16) = kr1;   // overlapped by compute
      *(uint4*)(Vb + s0 * 1024 + lane * 16) = vr0;
      *(uint4*)(Vb + s1 * 1024 + lane * 16) = vr1;
      __syncthreads();   // B: lgkm-only drain (fast)
    }
  }

  // ---- epilogue: each wave writes its own 32 queries' partials ----
#pragma unroll
  for (int dt = 0; dt < 4; dt++)
#pragma unroll
    for (int mt = 0; mt < 2; mt++)
#pragma unroll
      for (int r = 0; r < 4; r++) {
        int d = dt * 16 + q * 4 + r;
        int m = m0 + mt * 16 + c;
        float v = o[dt][mt][r];
        if (d < DW) {
          opart[(sp * DW + d) * NROWS + m] = f32_to_bf16_rne(v);
        } else if (d == 56) {
          esum_g[sp * NROWS + m] = v;   // softmax denominator (exact f32)
        }
      }
}

// ---------------------------------------------------------------------------
// Kernel 3: fused merge + pointwise + bias + residual.
// Grid (64 windows, 7 t-chunks of 7). For window g all 144 channels are
// contiguous in opart rows: r = g*144 + i.
// ---------------------------------------------------------------------------
__global__ __launch_bounds__(256) void fuse_pw_kernel(
    const ushort* __restrict__ opart, const float* __restrict__ esum_g,
    const float* __restrict__ x, const float* __restrict__ pw,
    const float* __restrict__ pb, float* __restrict__ out) {
  __shared__ float vb[7 * 145];
  __shared__ float inv_es[144];
  const int g = blockIdx.x, tch = blockIdx.y;
  const int t0 = tch * 7;
  const int tid = threadIdx.x;

  if (tid < 144) {
    int r = g * C3 + tid;
    float e = 0.f;
#pragma unroll
    for (int sp = 0; sp < NSPLIT; sp++) e += esum_g[sp * NROWS + r];
    inv_es[tid] = 1.f / e;
  }
  __syncthreads();

  for (int j = tid; j < 7 * 144; j += 256) {
    int tt = j / 144, i = j - tt * 144;
    int r = g * C3 + i, t = t0 + tt;
    float ov = 0.f;
#pragma unroll
    for (int sp = 0; sp < NSPLIT; sp++)
      ov += bf16_to_f32(opart[(sp * DW + t) * NROWS + r]);
    vb[tt * 145 + i] = ov * inv_es[i];
  }
  __syncthreads();

  for (int j = tid; j < C_IN * 7; j += 256) {
    int o = j / 7, tt = j - o * 7;
    int t = t0 + tt;
    const float* pwo = pw + o * C3;
    const float* vrow = &vb[tt * 145];
    float a0 = 0.f, a1 = 0.f, a2 = 0.f, a3 = 0.f;
#pragma unroll
    for (int i = 0; i < C3; i += 4) {
      float4 wv = *(const float4*)&pwo[i];
      a0 += wv.x * vrow[i];
      a1 += wv.y * vrow[i + 1];
      a2 += wv.z * vrow[i + 2];
      a3 += wv.w * vrow[i + 3];
    }
    float acc = (a0 + a1) + (a2 + a3);
    int nh = g >> 3, nw = g & 7;
    int th = t / 7, tw = t - th * 7;
    int oidx = o * SSP + (nh * 7 + th) * HW + (nw * 7 + tw);
    out[oidx] = x[oidx] + pb[o] + acc;
  }
}

// ---------------------------------------------------------------------------
extern "C" void kernel_launch(void* const* d_in, const int* in_sizes, int n_in,
                              void* d_out, int out_size, void* d_ws, size_t ws_size,
                              hipStream_t stream) {
  const float* x  = (const float*)d_in[0];
  const float* w3 = (const float*)d_in[1];
  const float* w5 = (const float*)d_in[2];
  const float* w7 = (const float*)d_in[3];
  const float* pw = (const float*)d_in[4];
  const float* pb = (const float*)d_in[5];
  float* out = (float*)d_out;
  char* ws = (char*)d_ws;

  ushort* yf    = (ushort*)(ws + YF_B);
  ushort* yfT   = (ushort*)(ws + YFT_B);
  ushort* opart = (ushort*)(ws + OPART_B);
  float*  esum  = (float*)(ws + ESUM_B);

  conv_kernel<<<(NROWS * DPAD) / 256, 256, 0, stream>>>(x, w3, w5, w7, yf, yfT);
  attn_kernel<<<dim3(NROWS / 128, NSPLIT), 256, 0, stream>>>(yf, yfT, opart, esum);
  fuse_pw_kernel<<<dim3(64, 7), 256, 0, stream>>>(opart, esum, x, pw, pb, out);
}

// Round 17
// 114.765 us; speedup vs baseline: 1.0719x; 1.0719x over previous
//
#include <hip/hip_runtime.h>

typedef unsigned int uint;
typedef unsigned short ushort;
typedef __attribute__((ext_vector_type(8))) short bf16x8;   // MFMA A/B frag (8 bf16)
typedef __attribute__((ext_vector_type(4))) float f32x4;    // MFMA C/D frag

// Problem constants
#define C_IN   48
#define C3     144
#define HW     56
#define SSP    3136
#define DW     49
#define DPAD   64            // padded head dim; yf cols 49..63 zero, yfT row 56 ones
#define NROWS  9216

// Attention (R11 config — session best, 115.5 us): block = 8 waves (512 thr)
// sharing one K/V double-buffer, 256 queries/block. Grid (36,12) = 432 blocks,
// LDS 69632 B -> 2 blocks/CU = 16 waves/CU, all co-resident (512 slots).
#define NSPLIT 12            // key splits
#define TPS    12            // tiles per split = 144/NSPLIT

#define CSC 0.02944245f      // 1/(49*ln2): exp2(qk*CSC)=exp(qk/49)

// ws layout (bytes):
//   yf    bf16 [9216][64]    : 0        .. 1179648
//   yfT   bf16 [64][9216]    : 1179648  .. 2359296
//   opart bf16 [12][49][9216]: 2359296  .. 13197312
//   esum  f32  [12][9216]    : 13197312 .. 13639680
#define YF_B    0
#define YFT_B   1179648
#define OPART_B 2359296
#define ESUM_B  (OPART_B + NSPLIT * DW * NROWS * 2)

__device__ __forceinline__ ushort f32_to_bf16_rne(float x) {
  uint b = __float_as_uint(x);
  b += 0x7fffu + ((b >> 16) & 1u);
  return (ushort)(b >> 16);
}
__device__ __forceinline__ float bf16_to_f32(ushort u) {
  return __uint_as_float(((uint)u) << 16);
}
__device__ __forceinline__ void async_copy16(const void* g, void* l) {
  __builtin_amdgcn_global_load_lds(
      (const __attribute__((address_space(1))) unsigned int*)g,
      (__attribute__((address_space(3))) unsigned int*)l, 16, 0, 0);
}

// ---------------------------------------------------------------------------
// Kernel 1: depthwise convs, thread per (r,t); 2304 blocks (9 waves/SIMD).
// yf[r][64] written coalesced. yfT written via in-block LDS transpose:
// block covers rows r0..r0+3 x all 64 t; after staging 4x64 in LDS, lanes
// 0..63 each store ushort4 (4 consecutive r) -> 64 8B sector-touches/block
// instead of the old 256 2B scattered stores (4x fewer write sectors).
// yf cols 49..63 = 0 (K/Q pad); yfT row 56 = 1.0 (softmax denom via PV MFMA).
// yfT rows 49-55/57-63 garbage: each feeds only its own discarded d.
// ---------------------------------------------------------------------------
__global__ __launch_bounds__(256) void conv_kernel(
    const float* __restrict__ x, const float* __restrict__ w3,
    const float* __restrict__ w5, const float* __restrict__ w7,
    ushort* __restrict__ yf, ushort* __restrict__ yfT) {
  __shared__ ushort tile[4][64];
  const int tid = threadIdx.x;
  const int idx = blockIdx.x * 256 + tid;     // r*64 + t
  const int r = idx >> 6, t = idx & 63;
  const int rr = r & 3;
  const int r0 = r & ~3;

  ushort ov = 0;
  if (t < DW) {
    int g = r / C3, c3 = r - g * C3;
    int flat = g * DW + t;
    int h = flat / HW, w = flat - h * HW;
    int grp = c3 / C_IN, c = c3 - grp * C_IN;
    const float* wk; int ks;
    if (grp == 0)      { wk = w3 + c * 9;  ks = 3; }
    else if (grp == 1) { wk = w5 + c * 25; ks = 5; }
    else               { wk = w7 + c * 49; ks = 7; }
    int p = ks >> 1;
    const float* xc = x + c * SSP;
    float val = 0.f;
    for (int dy = 0; dy < ks; dy++) {
      int hy = h + dy - p;
      if (hy < 0 || hy >= HW) continue;
      const float* xr = xc + hy * HW;
      const float* wr = wk + dy * ks;
      for (int dx = 0; dx < ks; dx++) {
        int wx = w + dx - p;
        if (wx < 0 || wx >= HW) continue;
        val += xr[wx] * wr[dx];
      }
    }
    ov = f32_to_bf16_rne(val);
  }
  yf[idx] = ov;          // coalesced (pad cols get 0)
  tile[rr][t] = ov;
  __syncthreads();

  if (tid < 64) {
    ushort4 v;
    if (tid == 56) {
      v.x = 0x3F80; v.y = 0x3F80; v.z = 0x3F80; v.w = 0x3F80;  // ones row
    } else {
      v.x = tile[0][tid]; v.y = tile[1][tid];
      v.z = tile[2][tid]; v.w = tile[3][tid];
    }
    *(ushort4*)&yfT[tid * NROWS + r0] = v;   // 8B store, 4 consecutive r
  }
}

// ---------------------------------------------------------------------------
// Kernel 2: MFMA flash attention (R11 verbatim — session best).
// Grid (36, 12): blockIdx.x = 256-query block, blockIdx.y = key split (12
// tiles of 64 keys). All 8 waves share one K/V double-buffer (staging
// amortized 8 ways); each wave owns 32 queries end-to-end.
// LDS: [Kbuf0 8K][Kbuf1 8K][Vbuf0 8K][Vbuf1 8K][P 8x32x72 ushort 36864B]
//    = 69632 B -> 2 blocks/CU = 16 waves/CU.
// K slab s (of 8): d-chunk s, addr s*1024 + key*16.
// V slab s (of 8): key-chunk s, addr s*1024 + d*16.
// yfT row 56 = ones => softmax denominator at d==56.
// ---------------------------------------------------------------------------
__global__ __launch_bounds__(512, 4) void attn_kernel(
    const ushort* __restrict__ yf, const ushort* __restrict__ yfT,
    ushort* __restrict__ opart, float* __restrict__ esum_g) {
  __shared__ __align__(16) char smem[69632];

  const int tid = threadIdx.x;
  const int w = tid >> 6, lane = tid & 63;
  const int q = lane >> 4, c = lane & 15;
  const int m0 = blockIdx.x * 256 + w * 32;   // this wave's 32 queries
  const int sp = blockIdx.y;
  ushort* Pm = (ushort*)(smem + 32768) + w * (32 * 72);

  // Q B-frags (pre-scaled by CSC): 16B loads straight from yf.
  bf16x8 qf[2][2];
#pragma unroll
  for (int mt = 0; mt < 2; mt++)
#pragma unroll
    for (int ds = 0; ds < 2; ds++) {
      bf16x8 raw = *(const bf16x8*)&yf[(m0 + mt * 16 + c) * 64 + ds * 32 + q * 8];
      short tmp[8];
#pragma unroll
      for (int j = 0; j < 8; j++)
        tmp[j] = (short)f32_to_bf16_rne(bf16_to_f32((ushort)raw[j]) * CSC);
      qf[mt][ds] = *(bf16x8*)tmp;
    }

  f32x4 o[4][2];
#pragma unroll
  for (int dt = 0; dt < 4; dt++)
#pragma unroll
    for (int mt = 0; mt < 2; mt++) o[dt][mt] = (f32x4)0.f;

  // this wave's DMA slabs: K slab w, V slab w (8 waves cover 8+8 slabs)
  // ---- stage tile 0 into buffer 0 ----
  {
    const int k0 = (sp * TPS) * 64;
    async_copy16(yf + (k0 + lane) * 64 + w * 8, smem + w * 1024);
    async_copy16(yfT + lane * NROWS + k0 + w * 8, smem + 16384 + w * 1024);
  }
  __syncthreads();

  for (int it = 0; it < TPS; it++) {
    const int cur = it & 1;
    // ---- fire DMA for next tile into the other buffer ----
    if (it + 1 < TPS) {
      const int k1 = (sp * TPS + it + 1) * 64;
      async_copy16(yf + (k1 + lane) * 64 + w * 8,
                   smem + (cur ^ 1) * 8192 + w * 1024);
      async_copy16(yfT + lane * NROWS + k1 + w * 8,
                   smem + 16384 + (cur ^ 1) * 8192 + w * 1024);
    }

    const char* Kb = smem + cur * 8192;
    const char* Vb = smem + 16384 + cur * 8192;

    // ---- S^T = K . Q^T (K frags from LDS) ----
    f32x4 s[4][2];
#pragma unroll
    for (int nt = 0; nt < 4; nt++) {
      bf16x8 a0 = *(const bf16x8*)(Kb + q * 1024 + (nt * 16 + c) * 16);
      bf16x8 a1 = *(const bf16x8*)(Kb + (4 + q) * 1024 + (nt * 16 + c) * 16);
      s[nt][0] = (f32x4)0.f; s[nt][1] = (f32x4)0.f;
      s[nt][0] = __builtin_amdgcn_mfma_f32_16x16x32_bf16(a0, qf[0][0], s[nt][0], 0, 0, 0);
      s[nt][1] = __builtin_amdgcn_mfma_f32_16x16x32_bf16(a0, qf[1][0], s[nt][1], 0, 0, 0);
      s[nt][0] = __builtin_amdgcn_mfma_f32_16x16x32_bf16(a1, qf[0][1], s[nt][0], 0, 0, 0);
      s[nt][1] = __builtin_amdgcn_mfma_f32_16x16x32_bf16(a1, qf[1][1], s[nt][1], 0, 0, 0);
    }

    // ---- p = exp2(s); pack bf16 P into wave-private LDS ----
#pragma unroll
    for (int nt = 0; nt < 4; nt++)
#pragma unroll
      for (int mt = 0; mt < 2; mt++) {
        f32x4 sv = s[nt][mt];
        float p0 = __builtin_amdgcn_exp2f(sv[0]);
        float p1 = __builtin_amdgcn_exp2f(sv[1]);
        float p2 = __builtin_amdgcn_exp2f(sv[2]);
        float p3 = __builtin_amdgcn_exp2f(sv[3]);
        uint d0 = (__float_as_uint(p0) >> 16) | (__float_as_uint(p1) & 0xffff0000u);
        uint d1 = (__float_as_uint(p2) >> 16) | (__float_as_uint(p3) & 0xffff0000u);
        *(uint2*)&Pm[(mt * 16 + c) * 72 + nt * 16 + q * 4] = make_uint2(d0, d1);
      }

    // ---- O^T += V^T . P^T (V frags from LDS) ----
    bf16x8 bp[2][2];
#pragma unroll
    for (int mt = 0; mt < 2; mt++)
#pragma unroll
      for (int nc = 0; nc < 2; nc++)
        bp[mt][nc] = *(const bf16x8*)&Pm[(mt * 16 + c) * 72 + nc * 32 + q * 8];
#pragma unroll
    for (int dt = 0; dt < 4; dt++) {
      bf16x8 v0 = *(const bf16x8*)(Vb + q * 1024 + (dt * 16 + c) * 16);
      bf16x8 v1 = *(const bf16x8*)(Vb + (4 + q) * 1024 + (dt * 16 + c) * 16);
      o[dt][0] = __builtin_amdgcn_mfma_f32_16x16x32_bf16(v0, bp[0][0], o[dt][0], 0, 0, 0);
      o[dt][1] = __builtin_amdgcn_mfma_f32_16x16x32_bf16(v0, bp[1][0], o[dt][1], 0, 0, 0);
      o[dt][0] = __builtin_amdgcn_mfma_f32_16x16x32_bf16(v1, bp[0][1], o[dt][0], 0, 0, 0);
      o[dt][1] = __builtin_amdgcn_mfma_f32_16x16x32_bf16(v1, bp[1][1], o[dt][1], 0, 0, 0);
    }

    // barrier: all waves done reading buf[cur]; drains next-tile DMA.
    if (it + 1 < TPS) __syncthreads();
  }

  // ---- epilogue: each wave writes its own 32 queries' partials ----
#pragma unroll
  for (int dt = 0; dt < 4; dt++)
#pragma unroll
    for (int mt = 0; mt < 2; mt++)
#pragma unroll
      for (int r = 0; r < 4; r++) {
        int d = dt * 16 + q * 4 + r;
        int m = m0 + mt * 16 + c;
        float v = o[dt][mt][r];
        if (d < DW) {
          opart[(sp * DW + d) * NROWS + m] = f32_to_bf16_rne(v);
        } else if (d == 56) {
          esum_g[sp * NROWS + m] = v;   // softmax denominator (exact f32)
        }
      }
}

// ---------------------------------------------------------------------------
// Kernel 3: fused merge + pointwise + bias + residual.
// Grid (64 windows, 7 t-chunks of 7). For window g all 144 channels are
// contiguous in opart rows: r = g*144 + i.
// ---------------------------------------------------------------------------
__global__ __launch_bounds__(256) void fuse_pw_kernel(
    const ushort* __restrict__ opart, const float* __restrict__ esum_g,
    const float* __restrict__ x, const float* __restrict__ pw,
    const float* __restrict__ pb, float* __restrict__ out) {
  __shared__ float vb[7 * 145];
  __shared__ float inv_es[144];
  const int g = blockIdx.x, tch = blockIdx.y;
  const int t0 = tch * 7;
  const int tid = threadIdx.x;

  if (tid < 144) {
    int r = g * C3 + tid;
    float e = 0.f;
#pragma unroll
    for (int sp = 0; sp < NSPLIT; sp++) e += esum_g[sp * NROWS + r];
    inv_es[tid] = 1.f / e;
  }
  __syncthreads();

  for (int j = tid; j < 7 * 144; j += 256) {
    int tt = j / 144, i = j - tt * 144;
    int r = g * C3 + i, t = t0 + tt;
    float ov = 0.f;
#pragma unroll
    for (int sp = 0; sp < NSPLIT; sp++)
      ov += bf16_to_f32(opart[(sp * DW + t) * NROWS + r]);
    vb[tt * 145 + i] = ov * inv_es[i];
  }
  __syncthreads();

  for (int j = tid; j < C_IN * 7; j += 256) {
    int o = j / 7, tt = j - o * 7;
    int t = t0 + tt;
    const float* pwo = pw + o * C3;
    const float* vrow = &vb[tt * 145];
    float a0 = 0.f, a1 = 0.f, a2 = 0.f, a3 = 0.f;
#pragma unroll
    for (int i = 0; i < C3; i += 4) {
      float4 wv = *(const float4*)&pwo[i];
      a0 += wv.x * vrow[i];
      a1 += wv.y * vrow[i + 1];
      a2 += wv.z * vrow[i + 2];
      a3 += wv.w * vrow[i + 3];
    }
    float acc = (a0 + a1) + (a2 + a3);
    int nh = g >> 3, nw = g & 7;
    int th = t / 7, tw = t - th * 7;
    int oidx = o * SSP + (nh * 7 + th) * HW + (nw * 7 + tw);
    out[oidx] = x[oidx] + pb[o] + acc;
  }
}

// ---------------------------------------------------------------------------
extern "C" void kernel_launch(void* const* d_in, const int* in_sizes, int n_in,
                              void* d_out, int out_size, void* d_ws, size_t ws_size,
                              hipStream_t stream) {
  const float* x  = (const float*)d_in[0];
  const float* w3 = (const float*)d_in[1];
  const float* w5 = (const float*)d_in[2];
  const float* w7 = (const float*)d_in[3];
  const float* pw = (const float*)d_in[4];
  const float* pb = (const float*)d_in[5];
  float* out = (float*)d_out;
  char* ws = (char*)d_ws;

  ushort* yf    = (ushort*)(ws + YF_B);
  ushort* yfT   = (ushort*)(ws + YFT_B);
  ushort* opart = (ushort*)(ws + OPART_B);
  float*  esum  = (float*)(ws + ESUM_B);

  conv_kernel<<<(NROWS * DPAD) / 256, 256, 0, stream>>>(x, w3, w5, w7, yf, yfT);
  attn_kernel<<<dim3(NROWS / 256, NSPLIT), 512, 0, stream>>>(yf, yfT, opart, esum);
  fuse_pw_kernel<<<dim3(64, 7), 256, 0, stream>>>(opart, esum, x, pw, pb, out);
}